// Round 1
// baseline (410.313 us; speedup 1.0000x reference)
//
#include <hip/hip_runtime.h>

#define N_NODES 8192
#define N_EDGES 262144
#define F_INDIM 128
#define HID 256
#define F_OUT 128
#define N_GRAPHS 64
#define WPR (N_NODES / 32)   // 256 words per bitmask row

// ---------------------------------------------------------------------------
// 1. Edge scatter into symmetric bitmask (dedup by construction)
// ---------------------------------------------------------------------------
__global__ __launch_bounds__(256) void scatter_edges(const int* __restrict__ ei,
                                                     unsigned int* __restrict__ mask) {
    int e = blockIdx.x * blockDim.x + threadIdx.x;
    if (e >= N_EDGES) return;
    int s = ei[e];
    int d = ei[N_EDGES + e];
    if ((unsigned)s >= N_NODES || (unsigned)d >= N_NODES) return;  // safety guard
    atomicOr(&mask[(size_t)s * WPR + (d >> 5)], 1u << (d & 31));
    atomicOr(&mask[(size_t)d * WPR + (s >> 5)], 1u << (s & 31));
}

// ---------------------------------------------------------------------------
// 2. Degree (popcount) + dis = rsqrt(deg+1); one wave per row
// ---------------------------------------------------------------------------
__global__ __launch_bounds__(256) void compute_dis(const unsigned int* __restrict__ mask,
                                                   float* __restrict__ dis) {
    int wave = (blockIdx.x * blockDim.x + threadIdx.x) >> 6;
    int lane = threadIdx.x & 63;
    if (wave >= N_NODES) return;
    const uint4* row = (const uint4*)(mask + (size_t)wave * WPR);
    uint4 v = row[lane];  // 64 lanes x 4 words = 256 words
    int c = __popc(v.x) + __popc(v.y) + __popc(v.z) + __popc(v.w);
    for (int off = 32; off; off >>= 1) c += __shfl_down(c, off);
    if (lane == 0) dis[wave] = rsqrtf((float)(c + 1));  // +1 for added identity
}

// ---------------------------------------------------------------------------
// 3. GEMM1: M1p[i][t] = dis[i] * (X[i,:] @ W1[:,t] + b1[t])   (dis folded)
//    block = one row, 256 threads = one output column each
// ---------------------------------------------------------------------------
__global__ __launch_bounds__(256) void gemm1(const float* __restrict__ X,
                                             const float* __restrict__ W1,
                                             const float* __restrict__ b1,
                                             const float* __restrict__ dis,
                                             float* __restrict__ M1p) {
    int i = blockIdx.x;
    int t = threadIdx.x;
    __shared__ float xs[F_INDIM];
    if (t < F_INDIM) xs[t] = X[(size_t)i * F_INDIM + t];
    __syncthreads();
    float acc = b1[t];
#pragma unroll 8
    for (int k = 0; k < F_INDIM; ++k) acc += xs[k] * W1[(size_t)k * HID + t];
    M1p[(size_t)i * HID + t] = dis[i] * acc;
}

// ---------------------------------------------------------------------------
// 4. SpMM1 + identity + relu: H[i] = relu(dis[i]*(sum_{j in M[i]} M1p[j] + M1p[i]))
//    block = one row, 256 threads = one column each; bit-scan of LDS-staged mask
// ---------------------------------------------------------------------------
__global__ __launch_bounds__(256) void spmm1_relu(const unsigned int* __restrict__ mask,
                                                  const float* __restrict__ M1p,
                                                  const float* __restrict__ dis,
                                                  float* __restrict__ H) {
    int i = blockIdx.x;
    int c = threadIdx.x;
    __shared__ unsigned int wbuf[WPR];
    wbuf[c] = mask[(size_t)i * WPR + c];
    __syncthreads();
    float acc = M1p[(size_t)i * HID + c];  // identity term (dis[i]*row_i already folded)
    for (int w = 0; w < WPR; ++w) {
        unsigned int word = wbuf[w];
        while (word) {
            int b = __ffs(word) - 1;
            word &= word - 1;
            int j = (w << 5) + b;
            acc += M1p[(size_t)j * HID + c];
        }
    }
    H[(size_t)i * HID + c] = fmaxf(dis[i] * acc, 0.0f);
}

// ---------------------------------------------------------------------------
// 5. GEMM2: M2p[i][t] = dis[i] * (H[i,:] @ W2[:,t] + b2[t])
// ---------------------------------------------------------------------------
__global__ __launch_bounds__(128) void gemm2(const float* __restrict__ H,
                                             const float* __restrict__ W2,
                                             const float* __restrict__ b2,
                                             const float* __restrict__ dis,
                                             float* __restrict__ M2p) {
    int i = blockIdx.x;
    int t = threadIdx.x;
    __shared__ float hs[HID];
    hs[t] = H[(size_t)i * HID + t];
    hs[t + 128] = H[(size_t)i * HID + t + 128];
    __syncthreads();
    float acc = b2[t];
#pragma unroll 8
    for (int k = 0; k < HID; ++k) acc += hs[k] * W2[(size_t)k * F_OUT + t];
    M2p[(size_t)i * F_OUT + t] = dis[i] * acc;
}

// ---------------------------------------------------------------------------
// 6. SpMM2 (no relu): H2[i] = dis[i]*(sum_{j in M[i]} M2p[j] + M2p[i])
// ---------------------------------------------------------------------------
__global__ __launch_bounds__(128) void spmm2(const unsigned int* __restrict__ mask,
                                             const float* __restrict__ M2p,
                                             const float* __restrict__ dis,
                                             float* __restrict__ H2) {
    int i = blockIdx.x;
    int c = threadIdx.x;
    __shared__ unsigned int wbuf[WPR];
    wbuf[c] = mask[(size_t)i * WPR + c];
    wbuf[c + 128] = mask[(size_t)i * WPR + c + 128];
    __syncthreads();
    float acc = M2p[(size_t)i * F_OUT + c];  // identity term
    for (int w = 0; w < WPR; ++w) {
        unsigned int word = wbuf[w];
        while (word) {
            int b = __ffs(word) - 1;
            word &= word - 1;
            int j = (w << 5) + b;
            acc += M2p[(size_t)j * F_OUT + c];
        }
    }
    H2[(size_t)i * F_OUT + c] = dis[i] * acc;
}

// ---------------------------------------------------------------------------
// 7. Mean pool per sorted segment: out[g][c] = mean_{batch[i]==g} H2[i][c]
// ---------------------------------------------------------------------------
__global__ __launch_bounds__(128) void pool_mean(const float* __restrict__ H2,
                                                 const int* __restrict__ batch,
                                                 float* __restrict__ out) {
    int g = blockIdx.x;
    int c = threadIdx.x;
    // lower_bound(batch, g)
    int lo = 0, hi = N_NODES;
    while (lo < hi) { int m = (lo + hi) >> 1; if (batch[m] < g) lo = m + 1; else hi = m; }
    int start = lo;
    hi = N_NODES;
    while (lo < hi) { int m = (lo + hi) >> 1; if (batch[m] < g + 1) lo = m + 1; else hi = m; }
    int end = lo;
    float s = 0.0f;
    for (int i = start; i < end; ++i) s += H2[(size_t)i * F_OUT + c];
    int cnt = end - start;
    out[(size_t)g * F_OUT + c] = s / (float)(cnt > 0 ? cnt : 1);
}

// ---------------------------------------------------------------------------
extern "C" void kernel_launch(void* const* d_in, const int* in_sizes, int n_in,
                              void* d_out, int out_size, void* d_ws, size_t ws_size,
                              hipStream_t stream) {
    const float* X  = (const float*)d_in[0];
    const float* W1 = (const float*)d_in[1];
    const float* b1 = (const float*)d_in[2];
    const float* W2 = (const float*)d_in[3];
    const float* b2 = (const float*)d_in[4];
    const int* ei    = (const int*)d_in[5];
    const int* batch = (const int*)d_in[6];
    float* out = (float*)d_out;

    char* ws = (char*)d_ws;
    unsigned int* mask = (unsigned int*)(ws);                  //  8 MB
    float* M1p = (float*)(ws + 8388608);                       //  8 MB (8192x256)
    float* H   = (float*)(ws + 16777216);                      //  8 MB (8192x256)
    float* M2p = (float*)(ws + 25165824);                      //  4 MB (8192x128)
    float* H2  = (float*)(ws + 29360128);                      //  4 MB (8192x128)
    float* dis = (float*)(ws + 33554432);                      // 32 KB

    hipMemsetAsync(mask, 0, (size_t)N_NODES * WPR * sizeof(unsigned int), stream);
    scatter_edges<<<N_EDGES / 256, 256, 0, stream>>>(ei, mask);
    compute_dis<<<N_NODES / 4, 256, 0, stream>>>(mask, dis);
    gemm1<<<N_NODES, 256, 0, stream>>>(X, W1, b1, dis, M1p);
    spmm1_relu<<<N_NODES, 256, 0, stream>>>(mask, M1p, dis, H);
    gemm2<<<N_NODES, 128, 0, stream>>>(H, W2, b2, dis, M2p);
    spmm2<<<N_NODES, 128, 0, stream>>>(mask, M2p, dis, H2);
    pool_mean<<<N_GRAPHS, 128, 0, stream>>>(H2, batch, out);
}

// Round 2
// 267.765 us; speedup vs baseline: 1.5324x; 1.5324x over previous
//
#include <hip/hip_runtime.h>

#define N_NODES 8192
#define N_EDGES 262144
#define F_INDIM 128
#define HID 256
#define F_OUT 128
#define N_GRAPHS 64
#define WPR (N_NODES / 32)   // 256 words per bitmask row
#define CAP 160              // max supported degree (Poisson(64), 12 sigma headroom)

// ---------------------------------------------------------------------------
// 1. Edge scatter into symmetric bitmask (dedup by construction)
// ---------------------------------------------------------------------------
__global__ __launch_bounds__(256) void scatter_edges(const int* __restrict__ ei,
                                                     unsigned int* __restrict__ mask) {
    int e = blockIdx.x * blockDim.x + threadIdx.x;
    if (e >= N_EDGES) return;
    int s = ei[e];
    int d = ei[N_EDGES + e];
    if ((unsigned)s >= N_NODES || (unsigned)d >= N_NODES) return;  // safety guard
    atomicOr(&mask[(size_t)s * WPR + (d >> 5)], 1u << (d & 31));
    atomicOr(&mask[(size_t)d * WPR + (s >> 5)], 1u << (s & 31));
}

// ---------------------------------------------------------------------------
// 2. Bitmask -> fixed-stride adjacency list + deg + dis. One wave per row.
//    Lane l owns words [4l..4l+3]; exclusive lane prefix-sum gives write base.
// ---------------------------------------------------------------------------
__global__ __launch_bounds__(256) void build_adj(const unsigned int* __restrict__ mask,
                                                 int* __restrict__ adj,
                                                 int* __restrict__ deg,
                                                 float* __restrict__ dis) {
    int row = (blockIdx.x * blockDim.x + threadIdx.x) >> 6;
    int lane = threadIdx.x & 63;
    if (row >= N_NODES) return;
    const uint4* r = (const uint4*)(mask + (size_t)row * WPR);
    uint4 v = r[lane];
    int cnt = __popc(v.x) + __popc(v.y) + __popc(v.z) + __popc(v.w);
    int scan = cnt;  // inclusive scan across 64 lanes
    for (int off = 1; off < 64; off <<= 1) {
        int n = __shfl_up(scan, off);
        if (lane >= off) scan += n;
    }
    int tot = __shfl(scan, 63);
    int idx = scan - cnt;  // exclusive prefix = my write base
    int* ap = adj + (size_t)row * CAP;
    int wbase = lane << 7;  // lane*4 words * 32 bits
    unsigned int wd;
    wd = v.x; while (wd) { int b = __ffs(wd) - 1; wd &= wd - 1; if (idx < CAP) ap[idx] = wbase + b;      ++idx; }
    wd = v.y; while (wd) { int b = __ffs(wd) - 1; wd &= wd - 1; if (idx < CAP) ap[idx] = wbase + 32 + b; ++idx; }
    wd = v.z; while (wd) { int b = __ffs(wd) - 1; wd &= wd - 1; if (idx < CAP) ap[idx] = wbase + 64 + b; ++idx; }
    wd = v.w; while (wd) { int b = __ffs(wd) - 1; wd &= wd - 1; if (idx < CAP) ap[idx] = wbase + 96 + b; ++idx; }
    if (lane == 63) { deg[row] = tot; dis[row] = rsqrtf((float)(tot + 1)); }  // +1: identity
}

// ---------------------------------------------------------------------------
// 3. GEMM1: M1p[i][t] = dis[i] * (X[i,:] @ W1[:,t] + b1[t])   (dis folded)
// ---------------------------------------------------------------------------
__global__ __launch_bounds__(256) void gemm1(const float* __restrict__ X,
                                             const float* __restrict__ W1,
                                             const float* __restrict__ b1,
                                             const float* __restrict__ dis,
                                             float* __restrict__ M1p) {
    int i = blockIdx.x;
    int t = threadIdx.x;
    __shared__ float xs[F_INDIM];
    if (t < F_INDIM) xs[t] = X[(size_t)i * F_INDIM + t];
    __syncthreads();
    float acc = b1[t];
#pragma unroll 8
    for (int k = 0; k < F_INDIM; ++k) acc += xs[k] * W1[(size_t)k * HID + t];
    M1p[(size_t)i * HID + t] = dis[i] * acc;
}

// ---------------------------------------------------------------------------
// 4. SpMM1 + identity + relu, CSR-style with 8-way ILP.
//    H[i] = relu(dis[i]*(sum_{j in adj[i]} M1p[j] + M1p[i]))
// ---------------------------------------------------------------------------
__global__ __launch_bounds__(256) void spmm1_relu(const int* __restrict__ adj,
                                                  const int* __restrict__ deg,
                                                  const float* __restrict__ M1p,
                                                  const float* __restrict__ dis,
                                                  float* __restrict__ H) {
    int i = blockIdx.x;
    int c = threadIdx.x;
    int d = deg[i];
    if (d > CAP) d = CAP;
    __shared__ int nb[CAP];
    if (c < d) nb[c] = adj[(size_t)i * CAP + c];
    __syncthreads();
    float a0 = M1p[(size_t)i * HID + c];  // identity term
    float a1 = 0.f, a2 = 0.f, a3 = 0.f, a4 = 0.f, a5 = 0.f, a6 = 0.f, a7 = 0.f;
    int k = 0;
    for (; k + 8 <= d; k += 8) {
        int j0 = nb[k],   j1 = nb[k+1], j2 = nb[k+2], j3 = nb[k+3];
        int j4 = nb[k+4], j5 = nb[k+5], j6 = nb[k+6], j7 = nb[k+7];
        a0 += M1p[(size_t)j0 * HID + c];
        a1 += M1p[(size_t)j1 * HID + c];
        a2 += M1p[(size_t)j2 * HID + c];
        a3 += M1p[(size_t)j3 * HID + c];
        a4 += M1p[(size_t)j4 * HID + c];
        a5 += M1p[(size_t)j5 * HID + c];
        a6 += M1p[(size_t)j6 * HID + c];
        a7 += M1p[(size_t)j7 * HID + c];
    }
    for (; k < d; ++k) a0 += M1p[(size_t)nb[k] * HID + c];
    float acc = ((a0 + a1) + (a2 + a3)) + ((a4 + a5) + (a6 + a7));
    H[(size_t)i * HID + c] = fmaxf(dis[i] * acc, 0.0f);
}

// ---------------------------------------------------------------------------
// 5. GEMM2: M2p[i][t] = dis[i] * (H[i,:] @ W2[:,t] + b2[t])
// ---------------------------------------------------------------------------
__global__ __launch_bounds__(128) void gemm2(const float* __restrict__ H,
                                             const float* __restrict__ W2,
                                             const float* __restrict__ b2,
                                             const float* __restrict__ dis,
                                             float* __restrict__ M2p) {
    int i = blockIdx.x;
    int t = threadIdx.x;
    __shared__ float hs[HID];
    hs[t] = H[(size_t)i * HID + t];
    hs[t + 128] = H[(size_t)i * HID + t + 128];
    __syncthreads();
    float acc = b2[t];
#pragma unroll 8
    for (int k = 0; k < HID; ++k) acc += hs[k] * W2[(size_t)k * F_OUT + t];
    M2p[(size_t)i * F_OUT + t] = dis[i] * acc;
}

// ---------------------------------------------------------------------------
// 6. SpMM2 (no relu), CSR-style with 8-way ILP.
// ---------------------------------------------------------------------------
__global__ __launch_bounds__(128) void spmm2(const int* __restrict__ adj,
                                             const int* __restrict__ deg,
                                             const float* __restrict__ M2p,
                                             const float* __restrict__ dis,
                                             float* __restrict__ H2) {
    int i = blockIdx.x;
    int c = threadIdx.x;
    int d = deg[i];
    if (d > CAP) d = CAP;
    __shared__ int nb[CAP];
    for (int t = c; t < d; t += 128) nb[t] = adj[(size_t)i * CAP + t];
    __syncthreads();
    float a0 = M2p[(size_t)i * F_OUT + c];  // identity term
    float a1 = 0.f, a2 = 0.f, a3 = 0.f, a4 = 0.f, a5 = 0.f, a6 = 0.f, a7 = 0.f;
    int k = 0;
    for (; k + 8 <= d; k += 8) {
        int j0 = nb[k],   j1 = nb[k+1], j2 = nb[k+2], j3 = nb[k+3];
        int j4 = nb[k+4], j5 = nb[k+5], j6 = nb[k+6], j7 = nb[k+7];
        a0 += M2p[(size_t)j0 * F_OUT + c];
        a1 += M2p[(size_t)j1 * F_OUT + c];
        a2 += M2p[(size_t)j2 * F_OUT + c];
        a3 += M2p[(size_t)j3 * F_OUT + c];
        a4 += M2p[(size_t)j4 * F_OUT + c];
        a5 += M2p[(size_t)j5 * F_OUT + c];
        a6 += M2p[(size_t)j6 * F_OUT + c];
        a7 += M2p[(size_t)j7 * F_OUT + c];
    }
    for (; k < d; ++k) a0 += M2p[(size_t)nb[k] * F_OUT + c];
    float acc = ((a0 + a1) + (a2 + a3)) + ((a4 + a5) + (a6 + a7));
    H2[(size_t)i * F_OUT + c] = dis[i] * acc;
}

// ---------------------------------------------------------------------------
// 7. Mean pool per sorted segment
// ---------------------------------------------------------------------------
__global__ __launch_bounds__(128) void pool_mean(const float* __restrict__ H2,
                                                 const int* __restrict__ batch,
                                                 float* __restrict__ out) {
    int g = blockIdx.x;
    int c = threadIdx.x;
    int lo = 0, hi = N_NODES;
    while (lo < hi) { int m = (lo + hi) >> 1; if (batch[m] < g) lo = m + 1; else hi = m; }
    int start = lo;
    hi = N_NODES;
    while (lo < hi) { int m = (lo + hi) >> 1; if (batch[m] < g + 1) lo = m + 1; else hi = m; }
    int end = lo;
    float s = 0.0f;
    for (int i = start; i < end; ++i) s += H2[(size_t)i * F_OUT + c];
    int cnt = end - start;
    out[(size_t)g * F_OUT + c] = s / (float)(cnt > 0 ? cnt : 1);
}

// ---------------------------------------------------------------------------
extern "C" void kernel_launch(void* const* d_in, const int* in_sizes, int n_in,
                              void* d_out, int out_size, void* d_ws, size_t ws_size,
                              hipStream_t stream) {
    const float* X  = (const float*)d_in[0];
    const float* W1 = (const float*)d_in[1];
    const float* b1 = (const float*)d_in[2];
    const float* W2 = (const float*)d_in[3];
    const float* b2 = (const float*)d_in[4];
    const int* ei    = (const int*)d_in[5];
    const int* batch = (const int*)d_in[6];
    float* out = (float*)d_out;

    char* ws = (char*)d_ws;
    // [0, 8MB): mask during build; reused later for M2p (4MB) + H2 (4MB)
    unsigned int* mask = (unsigned int*)(ws);
    float* M2p = (float*)(ws);                       // alias: written after mask dead
    float* H2  = (float*)(ws + 4194304);
    float* M1p = (float*)(ws + 8388608);             // 8 MB (8192x256)
    float* H   = (float*)(ws + 16777216);            // 8 MB (8192x256)
    int*   adj = (int*)(ws + 25165824);              // 5.25 MB (8192x160 int)
    int*   deg = (int*)(ws + 30408704);              // 32 KB
    float* dis = (float*)(ws + 30441472);            // 32 KB

    hipMemsetAsync(mask, 0, (size_t)N_NODES * WPR * sizeof(unsigned int), stream);
    scatter_edges<<<N_EDGES / 256, 256, 0, stream>>>(ei, mask);
    build_adj<<<N_NODES / 4, 256, 0, stream>>>(mask, adj, deg, dis);
    gemm1<<<N_NODES, 256, 0, stream>>>(X, W1, b1, dis, M1p);
    spmm1_relu<<<N_NODES, 256, 0, stream>>>(adj, deg, M1p, dis, H);
    gemm2<<<N_NODES, 128, 0, stream>>>(H, W2, b2, dis, M2p);
    spmm2<<<N_NODES, 128, 0, stream>>>(adj, deg, M2p, dis, H2);
    pool_mean<<<N_GRAPHS, 128, 0, stream>>>(H2, batch, out);
}

// Round 4
// 202.443 us; speedup vs baseline: 2.0268x; 1.3227x over previous
//
#include <hip/hip_runtime.h>

#define N_NODES 8192
#define N_EDGES 262144
#define F_INDIM 128
#define HID 256
#define F_OUT 128
#define N_GRAPHS 64
#define WPR (N_NODES / 32)   // 256 words per bitmask row
#define CAP 160              // max supported degree (Poisson(64), 12 sigma headroom)

// ---------------------------------------------------------------------------
// 1. Edge scatter into symmetric bitmask (dedup by construction)  [R2 proven]
// ---------------------------------------------------------------------------
__global__ __launch_bounds__(256) void scatter_edges(const int* __restrict__ ei,
                                                     unsigned int* __restrict__ mask) {
    int e = blockIdx.x * blockDim.x + threadIdx.x;
    if (e >= N_EDGES) return;
    int s = ei[e];
    int d = ei[N_EDGES + e];
    if ((unsigned)s >= N_NODES || (unsigned)d >= N_NODES) return;  // safety guard
    atomicOr(&mask[(size_t)s * WPR + (d >> 5)], 1u << (d & 31));
    atomicOr(&mask[(size_t)d * WPR + (s >> 5)], 1u << (s & 31));
}

// ---------------------------------------------------------------------------
// 2. Bitmask -> fixed-stride adjacency + deg + dis. One wave/row. [R2 proven]
// ---------------------------------------------------------------------------
__global__ __launch_bounds__(256) void build_adj(const unsigned int* __restrict__ mask,
                                                 int* __restrict__ adj,
                                                 int* __restrict__ deg,
                                                 float* __restrict__ dis) {
    int row = (blockIdx.x * blockDim.x + threadIdx.x) >> 6;
    int lane = threadIdx.x & 63;
    if (row >= N_NODES) return;
    const uint4* r = (const uint4*)(mask + (size_t)row * WPR);
    uint4 v = r[lane];
    int cnt = __popc(v.x) + __popc(v.y) + __popc(v.z) + __popc(v.w);
    int scan = cnt;  // inclusive scan across 64 lanes
    for (int off = 1; off < 64; off <<= 1) {
        int n = __shfl_up(scan, off);
        if (lane >= off) scan += n;
    }
    int tot = __shfl(scan, 63);
    int idx = scan - cnt;  // exclusive prefix = my write base
    int* ap = adj + (size_t)row * CAP;
    int wbase = lane << 7;  // lane*4 words * 32 bits
    unsigned int wd;
    wd = v.x; while (wd) { int b = __ffs(wd) - 1; wd &= wd - 1; if (idx < CAP) ap[idx] = wbase + b;      ++idx; }
    wd = v.y; while (wd) { int b = __ffs(wd) - 1; wd &= wd - 1; if (idx < CAP) ap[idx] = wbase + 32 + b; ++idx; }
    wd = v.z; while (wd) { int b = __ffs(wd) - 1; wd &= wd - 1; if (idx < CAP) ap[idx] = wbase + 64 + b; ++idx; }
    wd = v.w; while (wd) { int b = __ffs(wd) - 1; wd &= wd - 1; if (idx < CAP) ap[idx] = wbase + 96 + b; ++idx; }
    if (lane == 63) { deg[row] = tot; dis[row] = rsqrtf((float)(tot + 1)); }  // +1: identity
}

// ---------------------------------------------------------------------------
// 3. GEMM1 (4 rows/block): M1p[i][t] = dis[i]*(X[i,:]@W1[:,t] + b1[t])
//    Same math as R2 gemm1; W1 column read shared across 4 rows (L2 traffic /4)
// ---------------------------------------------------------------------------
__global__ __launch_bounds__(256) void gemm1_v2(const float* __restrict__ X,
                                                const float* __restrict__ W1,
                                                const float* __restrict__ b1,
                                                const float* __restrict__ dis,
                                                float* __restrict__ M1p) {
    int i0 = blockIdx.x * 4;
    int t = threadIdx.x;
    __shared__ float xs[4][F_INDIM];
    for (int v = t; v < 4 * F_INDIM; v += 256)
        xs[v >> 7][v & 127] = X[(size_t)(i0 + (v >> 7)) * F_INDIM + (v & 127)];
    __syncthreads();
    float bt = b1[t];
    float a0 = bt, a1 = bt, a2 = bt, a3 = bt;
#pragma unroll 8
    for (int k = 0; k < F_INDIM; ++k) {
        float w = W1[(size_t)k * HID + t];
        a0 += xs[0][k] * w;
        a1 += xs[1][k] * w;
        a2 += xs[2][k] * w;
        a3 += xs[3][k] * w;
    }
    M1p[(size_t)(i0 + 0) * HID + t] = dis[i0 + 0] * a0;
    M1p[(size_t)(i0 + 1) * HID + t] = dis[i0 + 1] * a1;
    M1p[(size_t)(i0 + 2) * HID + t] = dis[i0 + 2] * a2;
    M1p[(size_t)(i0 + 3) * HID + t] = dis[i0 + 3] * a3;
}

// ---------------------------------------------------------------------------
// 4. SpMM1 + relu, CSR 8-way ILP  [R2 proven]
// ---------------------------------------------------------------------------
__global__ __launch_bounds__(256) void spmm1_relu(const int* __restrict__ adj,
                                                  const int* __restrict__ deg,
                                                  const float* __restrict__ M1p,
                                                  const float* __restrict__ dis,
                                                  float* __restrict__ H) {
    int i = blockIdx.x;
    int c = threadIdx.x;
    int d = deg[i];
    if (d > CAP) d = CAP;
    __shared__ int nb[CAP];
    if (c < d) nb[c] = adj[(size_t)i * CAP + c];
    __syncthreads();
    float a0 = M1p[(size_t)i * HID + c];  // identity term
    float a1 = 0.f, a2 = 0.f, a3 = 0.f, a4 = 0.f, a5 = 0.f, a6 = 0.f, a7 = 0.f;
    int k = 0;
    for (; k + 8 <= d; k += 8) {
        int j0 = nb[k],   j1 = nb[k+1], j2 = nb[k+2], j3 = nb[k+3];
        int j4 = nb[k+4], j5 = nb[k+5], j6 = nb[k+6], j7 = nb[k+7];
        a0 += M1p[(size_t)j0 * HID + c];
        a1 += M1p[(size_t)j1 * HID + c];
        a2 += M1p[(size_t)j2 * HID + c];
        a3 += M1p[(size_t)j3 * HID + c];
        a4 += M1p[(size_t)j4 * HID + c];
        a5 += M1p[(size_t)j5 * HID + c];
        a6 += M1p[(size_t)j6 * HID + c];
        a7 += M1p[(size_t)j7 * HID + c];
    }
    for (; k < d; ++k) a0 += M1p[(size_t)nb[k] * HID + c];
    float acc = ((a0 + a1) + (a2 + a3)) + ((a4 + a5) + (a6 + a7));
    H[(size_t)i * HID + c] = fmaxf(dis[i] * acc, 0.0f);
}

// ---------------------------------------------------------------------------
// 5. GEMM2 (4 rows/block): M2p[i][t] = dis[i]*(H[i,:]@W2[:,t] + b2[t])
// ---------------------------------------------------------------------------
__global__ __launch_bounds__(128) void gemm2_v2(const float* __restrict__ H,
                                                const float* __restrict__ W2,
                                                const float* __restrict__ b2,
                                                const float* __restrict__ dis,
                                                float* __restrict__ M2p) {
    int i0 = blockIdx.x * 4;
    int t = threadIdx.x;
    __shared__ float hs[4][HID];
    for (int v = t; v < 4 * HID; v += 128)
        hs[v >> 8][v & 255] = H[(size_t)(i0 + (v >> 8)) * HID + (v & 255)];
    __syncthreads();
    float bt = b2[t];
    float a0 = bt, a1 = bt, a2 = bt, a3 = bt;
#pragma unroll 8
    for (int k = 0; k < HID; ++k) {
        float w = W2[(size_t)k * F_OUT + t];
        a0 += hs[0][k] * w;
        a1 += hs[1][k] * w;
        a2 += hs[2][k] * w;
        a3 += hs[3][k] * w;
    }
    M2p[(size_t)(i0 + 0) * F_OUT + t] = dis[i0 + 0] * a0;
    M2p[(size_t)(i0 + 1) * F_OUT + t] = dis[i0 + 1] * a1;
    M2p[(size_t)(i0 + 2) * F_OUT + t] = dis[i0 + 2] * a2;
    M2p[(size_t)(i0 + 3) * F_OUT + t] = dis[i0 + 3] * a3;
}

// ---------------------------------------------------------------------------
// 6. SpMM2, CSR 8-way ILP  [R2 proven]
// ---------------------------------------------------------------------------
__global__ __launch_bounds__(128) void spmm2(const int* __restrict__ adj,
                                             const int* __restrict__ deg,
                                             const float* __restrict__ M2p,
                                             const float* __restrict__ dis,
                                             float* __restrict__ H2) {
    int i = blockIdx.x;
    int c = threadIdx.x;
    int d = deg[i]; if (d > CAP) d = CAP;
    __shared__ int nb[CAP];
    for (int t = c; t < d; t += 128) nb[t] = adj[(size_t)i * CAP + t];
    __syncthreads();
    float a0 = M2p[(size_t)i * F_OUT + c];  // identity term
    float a1 = 0.f, a2 = 0.f, a3 = 0.f, a4 = 0.f, a5 = 0.f, a6 = 0.f, a7 = 0.f;
    int k = 0;
    for (; k + 8 <= d; k += 8) {
        int j0 = nb[k],   j1 = nb[k+1], j2 = nb[k+2], j3 = nb[k+3];
        int j4 = nb[k+4], j5 = nb[k+5], j6 = nb[k+6], j7 = nb[k+7];
        a0 += M2p[(size_t)j0 * F_OUT + c];
        a1 += M2p[(size_t)j1 * F_OUT + c];
        a2 += M2p[(size_t)j2 * F_OUT + c];
        a3 += M2p[(size_t)j3 * F_OUT + c];
        a4 += M2p[(size_t)j4 * F_OUT + c];
        a5 += M2p[(size_t)j5 * F_OUT + c];
        a6 += M2p[(size_t)j6 * F_OUT + c];
        a7 += M2p[(size_t)j7 * F_OUT + c];
    }
    for (; k < d; ++k) a0 += M2p[(size_t)nb[k] * F_OUT + c];
    float acc = ((a0 + a1) + (a2 + a3)) + ((a4 + a5) + (a6 + a7));
    H2[(size_t)i * F_OUT + c] = dis[i] * acc;
}

// ---------------------------------------------------------------------------
// 7. Pool stage A: partial sums, grid (graph, 16 chunks)
// ---------------------------------------------------------------------------
__global__ __launch_bounds__(128) void pool_a(const float* __restrict__ H2,
                                              const int* __restrict__ batch,
                                              float* __restrict__ part) {
    int g = blockIdx.x, s = blockIdx.y, c = threadIdx.x;
    int lo = 0, hi = N_NODES;
    while (lo < hi) { int m = (lo + hi) >> 1; if (batch[m] < g) lo = m + 1; else hi = m; }
    int start = lo;
    hi = N_NODES;
    while (lo < hi) { int m = (lo + hi) >> 1; if (batch[m] < g + 1) lo = m + 1; else hi = m; }
    int end = lo;
    int len = end - start;
    int chunk = (len + 15) >> 4;
    int a = start + s * chunk;
    int b = a + chunk; if (b > end) b = end;
    float sum = 0.0f;
    for (int i = a; i < b; ++i) sum += H2[(size_t)i * F_OUT + c];
    part[((size_t)g * 16 + s) * F_OUT + c] = sum;
}

// ---------------------------------------------------------------------------
// 8. Pool stage B: combine 16 partials, divide by count
// ---------------------------------------------------------------------------
__global__ __launch_bounds__(128) void pool_b(const float* __restrict__ part,
                                              const int* __restrict__ batch,
                                              float* __restrict__ out) {
    int g = blockIdx.x, c = threadIdx.x;
    int lo = 0, hi = N_NODES;
    while (lo < hi) { int m = (lo + hi) >> 1; if (batch[m] < g) lo = m + 1; else hi = m; }
    int start = lo;
    hi = N_NODES;
    while (lo < hi) { int m = (lo + hi) >> 1; if (batch[m] < g + 1) lo = m + 1; else hi = m; }
    int cnt = lo - start;
    float s = 0.0f;
#pragma unroll
    for (int t = 0; t < 16; ++t) s += part[((size_t)g * 16 + t) * F_OUT + c];
    out[(size_t)g * F_OUT + c] = s / (float)(cnt > 0 ? cnt : 1);
}

// ---------------------------------------------------------------------------
extern "C" void kernel_launch(void* const* d_in, const int* in_sizes, int n_in,
                              void* d_out, int out_size, void* d_ws, size_t ws_size,
                              hipStream_t stream) {
    const float* X  = (const float*)d_in[0];
    const float* W1 = (const float*)d_in[1];
    const float* b1 = (const float*)d_in[2];
    const float* W2 = (const float*)d_in[3];
    const float* b2 = (const float*)d_in[4];
    const int* ei    = (const int*)d_in[5];
    const int* batch = (const int*)d_in[6];
    float* out = (float*)d_out;

    char* ws = (char*)d_ws;
    // [0, 8MB): mask during build; reused later for M2p (4MB) + H2 (4MB)   [R2 proven aliasing]
    unsigned int* mask = (unsigned int*)(ws);
    float* M2p = (float*)(ws);                       // alias: written after mask dead
    float* H2  = (float*)(ws + 4194304);
    float* M1p = (float*)(ws + 8388608);             // 8 MB (8192x256)
    float* H   = (float*)(ws + 16777216);            // 8 MB (8192x256)
    int*   adj = (int*)(ws + 25165824);              // 5.25 MB (8192x160 int)
    int*   deg = (int*)(ws + 30408704);              // 32 KB
    float* dis = (float*)(ws + 30441472);            // 32 KB
    float* part = (float*)(ws + 30474240);           // 512 KB (64x16x128)

    hipMemsetAsync(mask, 0, (size_t)N_NODES * WPR * sizeof(unsigned int), stream);
    scatter_edges<<<N_EDGES / 256, 256, 0, stream>>>(ei, mask);
    build_adj<<<N_NODES / 4, 256, 0, stream>>>(mask, adj, deg, dis);
    gemm1_v2<<<N_NODES / 4, 256, 0, stream>>>(X, W1, b1, dis, M1p);
    spmm1_relu<<<N_NODES, 256, 0, stream>>>(adj, deg, M1p, dis, H);
    gemm2_v2<<<N_NODES / 4, 128, 0, stream>>>(H, W2, b2, dis, M2p);
    spmm2<<<N_NODES, 128, 0, stream>>>(adj, deg, M2p, dis, H2);
    pool_a<<<dim3(N_GRAPHS, 16), 128, 0, stream>>>(H2, batch, part);
    pool_b<<<N_GRAPHS, 128, 0, stream>>>(part, batch, out);
}

// Round 5
// 178.428 us; speedup vs baseline: 2.2996x; 1.1346x over previous
//
#include <hip/hip_runtime.h>

#define N_NODES 8192
#define N_EDGES 262144
#define F_INDIM 128
#define HID 256
#define F_OUT 128
#define N_GRAPHS 64
#define WPR (N_NODES / 32)   // 256 words per bitmask row
#define CAP 160              // max supported degree (Poisson(64), 12 sigma headroom)

// ---------------------------------------------------------------------------
// 1. Edge scatter into symmetric bitmask (dedup by construction)  [R2 proven]
// ---------------------------------------------------------------------------
__global__ __launch_bounds__(256) void scatter_edges(const int* __restrict__ ei,
                                                     unsigned int* __restrict__ mask) {
    int e = blockIdx.x * blockDim.x + threadIdx.x;
    if (e >= N_EDGES) return;
    int s = ei[e];
    int d = ei[N_EDGES + e];
    if ((unsigned)s >= N_NODES || (unsigned)d >= N_NODES) return;  // safety guard
    atomicOr(&mask[(size_t)s * WPR + (d >> 5)], 1u << (d & 31));
    atomicOr(&mask[(size_t)d * WPR + (s >> 5)], 1u << (s & 31));
}

// ---------------------------------------------------------------------------
// 2. Bitmask -> fixed-stride adjacency + deg + dis. One wave/row. [R2 proven]
// ---------------------------------------------------------------------------
__global__ __launch_bounds__(256) void build_adj(const unsigned int* __restrict__ mask,
                                                 int* __restrict__ adj,
                                                 int* __restrict__ deg,
                                                 float* __restrict__ dis) {
    int row = (blockIdx.x * blockDim.x + threadIdx.x) >> 6;
    int lane = threadIdx.x & 63;
    if (row >= N_NODES) return;
    const uint4* r = (const uint4*)(mask + (size_t)row * WPR);
    uint4 v = r[lane];
    int cnt = __popc(v.x) + __popc(v.y) + __popc(v.z) + __popc(v.w);
    int scan = cnt;  // inclusive scan across 64 lanes
    for (int off = 1; off < 64; off <<= 1) {
        int n = __shfl_up(scan, off);
        if (lane >= off) scan += n;
    }
    int tot = __shfl(scan, 63);
    int idx = scan - cnt;  // exclusive prefix = my write base
    int* ap = adj + (size_t)row * CAP;
    int wbase = lane << 7;  // lane*4 words * 32 bits
    unsigned int wd;
    wd = v.x; while (wd) { int b = __ffs(wd) - 1; wd &= wd - 1; if (idx < CAP) ap[idx] = wbase + b;      ++idx; }
    wd = v.y; while (wd) { int b = __ffs(wd) - 1; wd &= wd - 1; if (idx < CAP) ap[idx] = wbase + 32 + b; ++idx; }
    wd = v.z; while (wd) { int b = __ffs(wd) - 1; wd &= wd - 1; if (idx < CAP) ap[idx] = wbase + 64 + b; ++idx; }
    wd = v.w; while (wd) { int b = __ffs(wd) - 1; wd &= wd - 1; if (idx < CAP) ap[idx] = wbase + 96 + b; ++idx; }
    if (lane == 63) { deg[row] = tot; dis[row] = rsqrtf((float)(tot + 1)); }  // +1: identity
}

// ---------------------------------------------------------------------------
// 3. spmm_x + fused sv: G[i][c] = dis_i*(dis_i*X[i][c] + sum_j dis_j*X[j][c])
//                       sv[i]   = dis_i*(dis_i + sum_j dis_j)   ( = (A_hat@1)[i] )
//    CSR 8-way ILP gather on X (512B rows — half the traffic of gathering XW1)
// ---------------------------------------------------------------------------
__global__ __launch_bounds__(128) void spmm_x(const int* __restrict__ adj,
                                              const int* __restrict__ deg,
                                              const float* __restrict__ X,
                                              const float* __restrict__ dis,
                                              float* __restrict__ G,
                                              float* __restrict__ sv) {
    int i = blockIdx.x;
    int c = threadIdx.x;
    int d = deg[i]; if (d > CAP) d = CAP;
    __shared__ int nb[CAP];
    __shared__ float nbd[CAP];
    __shared__ float red[2];
    float p = 0.0f;
    for (int t = c; t < d; t += 128) {
        int j = adj[(size_t)i * CAP + t];
        float dj = dis[j];
        nb[t] = j; nbd[t] = dj;
        p += dj;
    }
    // reduce p across the two waves (for sv)
    for (int off = 32; off; off >>= 1) p += __shfl_down(p, off);
    if ((c & 63) == 0) red[c >> 6] = p;
    __syncthreads();  // covers nb, nbd, red
    float di = dis[i];
    if (c == 0) sv[i] = di * (di + red[0] + red[1]);
    float a0 = di * X[(size_t)i * F_INDIM + c];  // identity term
    float a1 = 0.f, a2 = 0.f, a3 = 0.f, a4 = 0.f, a5 = 0.f, a6 = 0.f, a7 = 0.f;
    int k = 0;
    for (; k + 8 <= d; k += 8) {
        int j0 = nb[k],   j1 = nb[k+1], j2 = nb[k+2], j3 = nb[k+3];
        int j4 = nb[k+4], j5 = nb[k+5], j6 = nb[k+6], j7 = nb[k+7];
        a0 += nbd[k]   * X[(size_t)j0 * F_INDIM + c];
        a1 += nbd[k+1] * X[(size_t)j1 * F_INDIM + c];
        a2 += nbd[k+2] * X[(size_t)j2 * F_INDIM + c];
        a3 += nbd[k+3] * X[(size_t)j3 * F_INDIM + c];
        a4 += nbd[k+4] * X[(size_t)j4 * F_INDIM + c];
        a5 += nbd[k+5] * X[(size_t)j5 * F_INDIM + c];
        a6 += nbd[k+6] * X[(size_t)j6 * F_INDIM + c];
        a7 += nbd[k+7] * X[(size_t)j7 * F_INDIM + c];
    }
    for (; k < d; ++k) a0 += nbd[k] * X[(size_t)nb[k] * F_INDIM + c];
    float acc = ((a0 + a1) + (a2 + a3)) + ((a4 + a5) + (a6 + a7));
    G[(size_t)i * F_INDIM + c] = di * acc;
}

// ---------------------------------------------------------------------------
// 4. GEMM1 (4 rows/block, R4-proven skeleton): H = relu(G@W1 + sv*b1)
// ---------------------------------------------------------------------------
__global__ __launch_bounds__(256) void gemm1_v3(const float* __restrict__ G,
                                                const float* __restrict__ W1,
                                                const float* __restrict__ b1,
                                                const float* __restrict__ sv,
                                                float* __restrict__ H) {
    int i0 = blockIdx.x * 4;
    int t = threadIdx.x;
    __shared__ float xs[4][F_INDIM];
    for (int v = t; v < 4 * F_INDIM; v += 256)
        xs[v >> 7][v & 127] = G[(size_t)(i0 + (v >> 7)) * F_INDIM + (v & 127)];
    __syncthreads();
    float bt = b1[t];
    float a0 = 0.f, a1 = 0.f, a2 = 0.f, a3 = 0.f;
#pragma unroll 8
    for (int k = 0; k < F_INDIM; ++k) {
        float w = W1[(size_t)k * HID + t];
        a0 += xs[0][k] * w;
        a1 += xs[1][k] * w;
        a2 += xs[2][k] * w;
        a3 += xs[3][k] * w;
    }
    H[(size_t)(i0 + 0) * HID + t] = fmaxf(a0 + sv[i0 + 0] * bt, 0.0f);
    H[(size_t)(i0 + 1) * HID + t] = fmaxf(a1 + sv[i0 + 1] * bt, 0.0f);
    H[(size_t)(i0 + 2) * HID + t] = fmaxf(a2 + sv[i0 + 2] * bt, 0.0f);
    H[(size_t)(i0 + 3) * HID + t] = fmaxf(a3 + sv[i0 + 3] * bt, 0.0f);
}

// ---------------------------------------------------------------------------
// 5. GEMM2 (4 rows/block): M2p[i][t] = dis[i]*(H[i,:]@W2[:,t] + b2[t])  [R4 verbatim]
// ---------------------------------------------------------------------------
__global__ __launch_bounds__(128) void gemm2_v2(const float* __restrict__ H,
                                                const float* __restrict__ W2,
                                                const float* __restrict__ b2,
                                                const float* __restrict__ dis,
                                                float* __restrict__ M2p) {
    int i0 = blockIdx.x * 4;
    int t = threadIdx.x;
    __shared__ float hs[4][HID];
    for (int v = t; v < 4 * HID; v += 128)
        hs[v >> 8][v & 255] = H[(size_t)(i0 + (v >> 8)) * HID + (v & 255)];
    __syncthreads();
    float bt = b2[t];
    float a0 = bt, a1 = bt, a2 = bt, a3 = bt;
#pragma unroll 8
    for (int k = 0; k < HID; ++k) {
        float w = W2[(size_t)k * F_OUT + t];
        a0 += hs[0][k] * w;
        a1 += hs[1][k] * w;
        a2 += hs[2][k] * w;
        a3 += hs[3][k] * w;
    }
    M2p[(size_t)(i0 + 0) * F_OUT + t] = dis[i0 + 0] * a0;
    M2p[(size_t)(i0 + 1) * F_OUT + t] = dis[i0 + 1] * a1;
    M2p[(size_t)(i0 + 2) * F_OUT + t] = dis[i0 + 2] * a2;
    M2p[(size_t)(i0 + 3) * F_OUT + t] = dis[i0 + 3] * a3;
}

// ---------------------------------------------------------------------------
// 6. SpMM2, CSR 8-way ILP  [R4 verbatim]
// ---------------------------------------------------------------------------
__global__ __launch_bounds__(128) void spmm2(const int* __restrict__ adj,
                                             const int* __restrict__ deg,
                                             const float* __restrict__ M2p,
                                             const float* __restrict__ dis,
                                             float* __restrict__ H2) {
    int i = blockIdx.x;
    int c = threadIdx.x;
    int d = deg[i]; if (d > CAP) d = CAP;
    __shared__ int nb[CAP];
    for (int t = c; t < d; t += 128) nb[t] = adj[(size_t)i * CAP + t];
    __syncthreads();
    float a0 = M2p[(size_t)i * F_OUT + c];  // identity term
    float a1 = 0.f, a2 = 0.f, a3 = 0.f, a4 = 0.f, a5 = 0.f, a6 = 0.f, a7 = 0.f;
    int k = 0;
    for (; k + 8 <= d; k += 8) {
        int j0 = nb[k],   j1 = nb[k+1], j2 = nb[k+2], j3 = nb[k+3];
        int j4 = nb[k+4], j5 = nb[k+5], j6 = nb[k+6], j7 = nb[k+7];
        a0 += M2p[(size_t)j0 * F_OUT + c];
        a1 += M2p[(size_t)j1 * F_OUT + c];
        a2 += M2p[(size_t)j2 * F_OUT + c];
        a3 += M2p[(size_t)j3 * F_OUT + c];
        a4 += M2p[(size_t)j4 * F_OUT + c];
        a5 += M2p[(size_t)j5 * F_OUT + c];
        a6 += M2p[(size_t)j6 * F_OUT + c];
        a7 += M2p[(size_t)j7 * F_OUT + c];
    }
    for (; k < d; ++k) a0 += M2p[(size_t)nb[k] * F_OUT + c];
    float acc = ((a0 + a1) + (a2 + a3)) + ((a4 + a5) + (a6 + a7));
    H2[(size_t)i * F_OUT + c] = dis[i] * acc;
}

// ---------------------------------------------------------------------------
// 7. Pool stage A: partial sums, grid (graph, 16 chunks)  [R4 verbatim]
// ---------------------------------------------------------------------------
__global__ __launch_bounds__(128) void pool_a(const float* __restrict__ H2,
                                              const int* __restrict__ batch,
                                              float* __restrict__ part) {
    int g = blockIdx.x, s = blockIdx.y, c = threadIdx.x;
    int lo = 0, hi = N_NODES;
    while (lo < hi) { int m = (lo + hi) >> 1; if (batch[m] < g) lo = m + 1; else hi = m; }
    int start = lo;
    hi = N_NODES;
    while (lo < hi) { int m = (lo + hi) >> 1; if (batch[m] < g + 1) lo = m + 1; else hi = m; }
    int end = lo;
    int len = end - start;
    int chunk = (len + 15) >> 4;
    int a = start + s * chunk;
    int b = a + chunk; if (b > end) b = end;
    float sum = 0.0f;
    for (int i = a; i < b; ++i) sum += H2[(size_t)i * F_OUT + c];
    part[((size_t)g * 16 + s) * F_OUT + c] = sum;
}

// ---------------------------------------------------------------------------
// 8. Pool stage B: combine 16 partials, divide by count  [R4 verbatim]
// ---------------------------------------------------------------------------
__global__ __launch_bounds__(128) void pool_b(const float* __restrict__ part,
                                              const int* __restrict__ batch,
                                              float* __restrict__ out) {
    int g = blockIdx.x, c = threadIdx.x;
    int lo = 0, hi = N_NODES;
    while (lo < hi) { int m = (lo + hi) >> 1; if (batch[m] < g) lo = m + 1; else hi = m; }
    int start = lo;
    hi = N_NODES;
    while (lo < hi) { int m = (lo + hi) >> 1; if (batch[m] < g + 1) lo = m + 1; else hi = m; }
    int cnt = lo - start;
    float s = 0.0f;
#pragma unroll
    for (int t = 0; t < 16; ++t) s += part[((size_t)g * 16 + t) * F_OUT + c];
    out[(size_t)g * F_OUT + c] = s / (float)(cnt > 0 ? cnt : 1);
}

// ---------------------------------------------------------------------------
extern "C" void kernel_launch(void* const* d_in, const int* in_sizes, int n_in,
                              void* d_out, int out_size, void* d_ws, size_t ws_size,
                              hipStream_t stream) {
    const float* X  = (const float*)d_in[0];
    const float* W1 = (const float*)d_in[1];
    const float* b1 = (const float*)d_in[2];
    const float* W2 = (const float*)d_in[3];
    const float* b2 = (const float*)d_in[4];
    const int* ei    = (const int*)d_in[5];
    const int* batch = (const int*)d_in[6];
    float* out = (float*)d_out;

    char* ws = (char*)d_ws;
    // [0, 8MB): mask during build; reused later for M2p (4MB) + H2 (4MB)
    unsigned int* mask = (unsigned int*)(ws);
    float* M2p = (float*)(ws);                       // alias: written after mask dead
    float* H2  = (float*)(ws + 4194304);
    float* G   = (float*)(ws + 8388608);             // 4 MB (8192x128)
    float* H   = (float*)(ws + 16777216);            // 8 MB (8192x256)
    int*   adj = (int*)(ws + 25165824);              // 5.25 MB (8192x160 int)
    int*   deg = (int*)(ws + 30408704);              // 32 KB
    float* dis = (float*)(ws + 30441472);            // 32 KB
    float* part = (float*)(ws + 30474240);           // 512 KB (64x16x128)
    float* sv  = (float*)(ws + 30998528);            // 32 KB

    hipMemsetAsync(mask, 0, (size_t)N_NODES * WPR * sizeof(unsigned int), stream);
    scatter_edges<<<N_EDGES / 256, 256, 0, stream>>>(ei, mask);
    build_adj<<<N_NODES / 4, 256, 0, stream>>>(mask, adj, deg, dis);
    spmm_x<<<N_NODES, 128, 0, stream>>>(adj, deg, X, dis, G, sv);
    gemm1_v3<<<N_NODES / 4, 256, 0, stream>>>(G, W1, b1, sv, H);
    gemm2_v2<<<N_NODES / 4, 128, 0, stream>>>(H, W2, b2, dis, M2p);
    spmm2<<<N_NODES, 128, 0, stream>>>(adj, deg, M2p, dis, H2);
    pool_a<<<dim3(N_GRAPHS, 16), 128, 0, stream>>>(H2, batch, part);
    pool_b<<<N_GRAPHS, 128, 0, stream>>>(part, batch, out);
}